// Round 1
// baseline (534.772 us; speedup 1.0000x reference)
//
#include <hip/hip_runtime.h>

#define NL 21
#define NC 256
#define NB 64

// ---------------- pooling kernel: one block per (b,c) plane ----------------
__global__ __launch_bounds__(256) void pool_kernel(const float* __restrict__ feat,
                                                   const float* __restrict__ pre,
                                                   float* __restrict__ acc /* [21][256] */) {
    const int blk = blockIdx.x;          // 0 .. 64*256-1
    const int b = blk >> 8;              // batch
    const int c = blk & 255;             // channel

    __shared__ float plane[64 * 68];     // row stride 68: float4-aligned, bank-rotating
    __shared__ float part[256];
    __shared__ int s_left[NL], s_right[NL], s_down[NL], s_upper[NL];
    __shared__ float s_invs[NL];

    const int t = threadIdx.x;

    // landmark bounds (faithful quirks: x -> H axis, y -> W axis; trunc casts;
    // inclusive divisor, exclusive sum)
    if (t < NL) {
        const float x = pre[(b * NL + t) * 2 + 0];
        const float y = pre[(b * NL + t) * 2 + 1];
        const int down  = (int)fmaxf(y - 6.0f, 0.0f);
        const int left  = (int)fmaxf(x - 6.0f, 0.0f);
        const int upper = (int)fminf(y + 6.0f, 63.0f);
        const int right = (int)fminf(x + 6.0f, 63.0f);
        s_left[t] = left; s_right[t] = right; s_down[t] = down; s_upper[t] = upper;
        s_invs[t] = 1.0f / (float)((upper - down + 1) * (right - left + 1));
    }

    // cooperative plane load: 4096 floats = 1024 float4, 4 per thread
    const float4* __restrict__ src =
        (const float4*)(feat + ((size_t)b * NC + c) * 4096);
#pragma unroll
    for (int k = 0; k < 4; ++k) {
        const int f = t + k * 256;       // float4 index 0..1023
        const int row = f >> 4;          // 16 float4 per row
        const int col4 = f & 15;
        const float4 v = src[f];
        float* dst = &plane[row * 68 + col4 * 4];
        dst[0] = v.x; dst[1] = v.y; dst[2] = v.z; dst[3] = v.w;
    }
    __syncthreads();

    // (landmark, row) partial sums: 21*12 = 252 active threads
    float val = 0.0f;
    if (t < NL * 12) {
        const int l = t / 12;
        const int k = t - l * 12;
        const int h = s_left[l] + k;
        if (h < s_right[l]) {
            const float* row = &plane[h * 68];
            const int d = s_down[l], u = s_upper[l];
            float s = 0.0f;
            for (int w = d; w < u; ++w) s += row[w];
            val = s;
        }
    }
    part[t] = val;
    __syncthreads();

    // fold 12 row-partials per landmark, scale by inv_s, accumulate over batch
    if (t < NL) {
        float r = 0.0f;
#pragma unroll
        for (int k = 0; k < 12; ++k) r += part[t * 12 + k];
        atomicAdd(&acc[t * NC + c], r * s_invs[t]);
    }
}

// ---------------- finish kernel: EMA + log_softmax + KL ----------------
__device__ __forceinline__ float wave_sum(float v) {
#pragma unroll
    for (int o = 32; o > 0; o >>= 1) v += __shfl_xor(v, o, 64);
    return v;
}
__device__ __forceinline__ float wave_max(float v) {
#pragma unroll
    for (int o = 32; o > 0; o >>= 1) v = fmaxf(v, __shfl_xor(v, o, 64));
    return v;
}

__device__ __forceinline__ float block_sum(float v, float* red) {
    v = wave_sum(v);
    const int wave = threadIdx.x >> 6, lane = threadIdx.x & 63;
    __syncthreads();
    if (lane == 0) red[wave] = v;
    __syncthreads();
    return red[0] + red[1] + red[2] + red[3];
}
__device__ __forceinline__ float block_max(float v, float* red) {
    v = wave_max(v);
    const int wave = threadIdx.x >> 6, lane = threadIdx.x & 63;
    __syncthreads();
    if (lane == 0) red[wave] = v;
    __syncthreads();
    return fmaxf(fmaxf(red[0], red[1]), fmaxf(red[2], red[3]));
}

__global__ __launch_bounds__(256) void finish_kernel(const float* __restrict__ acc1,
                                                     const float* __restrict__ acc2,
                                                     const float* __restrict__ fea1,
                                                     const float* __restrict__ fea2,
                                                     float* __restrict__ out) {
    const int c = threadIdx.x;           // exactly 256 channels
    __shared__ float red[4];

    double total = 0.0;
    for (int l = 0; l < NL; ++l) {
        const int idx = l * NC + c;
        const float x1 = 0.999f * (acc1[idx] * (1.0f / 64.0f)) + 0.001f * fea1[idx];
        const float x2 = 0.999f * (acc2[idx] * (1.0f / 64.0f)) + 0.001f * fea2[idx];

        // log_softmax of row of fea_c1
        const float m = block_max(x1, red);
        const float e = __expf(x1 - m);
        const float se = block_sum(e, red);
        const float logZ = m + logf(se);
        const float logp = x1 - logZ;

        // q = fea_c2 / rowsum
        const float ssum = block_sum(x2, red);
        const float q = x2 / ssum;

        const float kl = (q > 0.0f) ? q * (logf(q) - logp) : 0.0f;
        const float klrow = block_sum(kl, red);
        total += (double)klrow;
    }
    if (c == 0) out[0] = (float)(total / 21.0);
}

extern "C" void kernel_launch(void* const* d_in, const int* in_sizes, int n_in,
                              void* d_out, int out_size, void* d_ws, size_t ws_size,
                              hipStream_t stream) {
    const float* f1   = (const float*)d_in[0];
    const float* f2   = (const float*)d_in[1];
    const float* pre1 = (const float*)d_in[2];
    const float* pre2 = (const float*)d_in[3];
    const float* fea1 = (const float*)d_in[4];
    const float* fea2 = (const float*)d_in[5];
    float* out = (float*)d_out;

    float* acc1 = (float*)d_ws;
    float* acc2 = acc1 + NL * NC;

    hipMemsetAsync(d_ws, 0, 2 * NL * NC * sizeof(float), stream);

    const dim3 grid(NB * NC), block(256);
    pool_kernel<<<grid, block, 0, stream>>>(f1, pre1, acc1);
    pool_kernel<<<grid, block, 0, stream>>>(f2, pre2, acc2);
    finish_kernel<<<1, 256, 0, stream>>>(acc1, acc2, fea1, fea2, out);
}